// Round 1
// baseline (257.574 us; speedup 1.0000x reference)
//
#include <hip/hip_runtime.h>

// N=64, T=2048, D=256, fp32. out = [context (N*D)] ++ [norm_attention (N*T)].
// softmax+mask+renorm == softmax restricted to t < lens[n]; attn == 0 past lens.
// Wave-autonomous split-softmax, 2 kernels, no atomics/memset, no barriers in K1:
//  K1: each WAVE owns a 16-row chunk: e = K·q (4 rows/pass, 16-lane butterfly),
//      in-register chunk softmax (2 cross-group shuffles for m and Z),
//      p broadcast via __shfl, O_c = p·V into one f4/lane, direct store.
//      Zero __shared__, zero __syncthreads. K/V loads nontemporal; loads past
//      lens skipped (group-uniform guards).
//  K2 (n, quarter): merge 128 chunk stats -> s_c = exp(m_c-m)/Z; attn = p*s_c
//      (explicit 0 past lens); context = sum_c s_c * O_c (invalid chunks
//      branch-skipped -> poison-proof).

#define N_B 64
#define T_S 2048
#define D_S 256
#define TPB 256
#define RC 16           // rows per wave-chunk
#define NCH (T_S / RC)  // 128 chunks per n

typedef __attribute__((ext_vector_type(4))) float f4;
typedef __attribute__((ext_vector_type(2))) float f2;

__device__ __forceinline__ f4 ntload4(const float* p) {
  return __builtin_nontemporal_load((const f4*)p);
}
__device__ __forceinline__ f4 fma4(float s, f4 a, f4 b) {
  b.x = fmaf(s, a.x, b.x);
  b.y = fmaf(s, a.y, b.y);
  b.z = fmaf(s, a.z, b.z);
  b.w = fmaf(s, a.w, b.w);
  return b;
}

__global__ __launch_bounds__(TPB) void fused_kernel(
    const float* __restrict__ q, const float* __restrict__ k,
    const float* __restrict__ v, const int* __restrict__ lens,
    float* __restrict__ p_out, float2* __restrict__ mzc,
    float* __restrict__ Oc) {
  const int n = blockIdx.y;
  const int L = lens[n];
  const int wave = threadIdx.x >> 6, lane = threadIdx.x & 63;
  const int c16 = blockIdx.x * 4 + wave;  // global 16-row chunk id
  const int r0 = c16 * RC;
  if (r0 >= L) return;  // whole-wave exit; no barriers anywhere -> safe
  const int tendw = min(r0 + RC, L);
  const int s = lane & 15, qd = lane >> 4;

  // q fragment for the 16-lane dot layout: dims i*64 + s*4 .. +3, i=0..3.
  // Cached loads (L1/L2-hot across the 32 blocks of this n).
  const f4* qp = (const f4*)(q + (size_t)n * D_S);
  const f4 qv0 = qp[s], qv1 = qp[s + 16], qv2 = qp[s + 32], qv3 = qp[s + 48];

  // ---- energies: rows r0 + qd + 4g, 16-lane butterfly per row group.
  // Guard is uniform within each 16-lane group (r depends only on qd,g).
  const float* kb = k + (size_t)n * T_S * D_S + s * 4;
  float e0 = -1e30f, e1 = -1e30f, e2 = -1e30f, e3 = -1e30f;
#define EROW(G, EV)                                                      \
  {                                                                      \
    const int r = r0 + qd + 4 * (G);                                     \
    if (r < tendw) {                                                     \
      const float* krow = kb + (size_t)r * D_S;                          \
      const f4 k0 = ntload4(krow);                                       \
      const f4 k1 = ntload4(krow + 64);                                  \
      const f4 k2 = ntload4(krow + 128);                                 \
      const f4 k3 = ntload4(krow + 192);                                 \
      float a = k0.x * qv0.x;                                            \
      a = fmaf(k0.y, qv0.y, a);                                          \
      a = fmaf(k0.z, qv0.z, a);                                          \
      a = fmaf(k0.w, qv0.w, a);                                          \
      a = fmaf(k1.x, qv1.x, a);                                          \
      a = fmaf(k1.y, qv1.y, a);                                          \
      a = fmaf(k1.z, qv1.z, a);                                          \
      a = fmaf(k1.w, qv1.w, a);                                          \
      a = fmaf(k2.x, qv2.x, a);                                          \
      a = fmaf(k2.y, qv2.y, a);                                          \
      a = fmaf(k2.z, qv2.z, a);                                          \
      a = fmaf(k2.w, qv2.w, a);                                          \
      a = fmaf(k3.x, qv3.x, a);                                          \
      a = fmaf(k3.y, qv3.y, a);                                          \
      a = fmaf(k3.z, qv3.z, a);                                          \
      a = fmaf(k3.w, qv3.w, a);                                          \
      a += __shfl_xor(a, 8, 64);                                         \
      a += __shfl_xor(a, 4, 64);                                         \
      a += __shfl_xor(a, 2, 64);                                         \
      a += __shfl_xor(a, 1, 64);                                         \
      EV = a;                                                            \
    }                                                                    \
  }
  EROW(0, e0)
  EROW(1, e1)
  EROW(2, e2)
  EROW(3, e3)
#undef EROW

  // ---- in-register chunk softmax (e uniform within each 16-lane group;
  // two xor-shuffles reduce across the 4 groups).
  float m = fmaxf(fmaxf(e0, e1), fmaxf(e2, e3));
  m = fmaxf(m, __shfl_xor(m, 16, 64));
  m = fmaxf(m, __shfl_xor(m, 32, 64));
  const float p0 = __expf(e0 - m), p1 = __expf(e1 - m);
  const float p2 = __expf(e2 - m), p3 = __expf(e3 - m);
  float z = (p0 + p1) + (p2 + p3);
  z += __shfl_xor(z, 16, 64);
  z += __shfl_xor(z, 32, 64);

  // unscaled p out (invalid rows write 0; merge masks t>=L explicitly anyway)
  if (s < 4) {
    float pv = p0;
    pv = (s == 1) ? p1 : pv;
    pv = (s == 2) ? p2 : pv;
    pv = (s == 3) ? p3 : pv;
    p_out[(size_t)n * T_S + r0 + qd + 4 * s] = pv;
  }
  if (lane == 0) mzc[n * NCH + c16] = make_float2(m, z);

  // ---- O_c = sum_r p_r * V[r][:]: lane owns dims [4*lane, 4*lane+4).
  // sc broadcast from group leader; sc==0 (rows past tendw, or underflow)
  // skips the load wave-uniformly.
  const float* vb = v + (size_t)n * T_S * D_S + (size_t)r0 * D_S + lane * 4;
  f4 aA = {0.f, 0.f, 0.f, 0.f}, aB = aA;
#define VROW(G, Q2, ACC)                                                   \
  {                                                                       \
    const float sc = __shfl(p##G, (Q2)*16, 64); /* row (Q2)+4*(G) */      \
    if (sc != 0.f)                                                        \
      ACC = fma4(sc, ntload4(vb + (size_t)((Q2) + 4 * (G)) * D_S), ACC);  \
  }
  VROW(0, 0, aA) VROW(0, 1, aB) VROW(0, 2, aA) VROW(0, 3, aB)
  VROW(1, 0, aA) VROW(1, 1, aB) VROW(1, 2, aA) VROW(1, 3, aB)
  VROW(2, 0, aA) VROW(2, 1, aB) VROW(2, 2, aA) VROW(2, 3, aB)
  VROW(3, 0, aA) VROW(3, 1, aB) VROW(3, 2, aA) VROW(3, 3, aB)
#undef VROW

  ((f4*)(Oc + ((size_t)(n * NCH + c16)) * D_S))[lane] = aA + aB;
}

// ---- merge: grid (4, N). Block (cx,n): attn t-slice [cx*512, +512),
// ctx d-slice [cx*64, +64). 128 chunk stats recomputed per block (L2-hot).
__global__ __launch_bounds__(TPB) void merge_kernel(
    const int* __restrict__ lens, const float* __restrict__ p_in,
    const float2* __restrict__ mzc, const float* __restrict__ Oc,
    float* __restrict__ out_ctx, float* __restrict__ out_attn) {
  const int n = blockIdx.y, cx = blockIdx.x;
  const int L = lens[n];
  const int nc = (L + RC - 1) / RC;
  const int tid = threadIdx.x;
  __shared__ float s_sh[NCH];
  __shared__ float cpart[TPB];

  if (tid < 64) {
    float m0 = -1e30f, z0 = 0.f, m1 = -1e30f, z1 = 0.f;
    if (tid < nc) {
      const float2 a = mzc[n * NCH + tid];
      m0 = a.x;
      z0 = a.y;
    }
    if (tid + 64 < nc) {
      const float2 a = mzc[n * NCH + tid + 64];
      m1 = a.x;
      z1 = a.y;
    }
    float M = fmaxf(m0, m1);
#pragma unroll
    for (int off = 32; off > 0; off >>= 1) M = fmaxf(M, __shfl_xor(M, off, 64));
    const float sc0 = __expf(m0 - M), sc1 = __expf(m1 - M);  // 0 for invalid
    float zs = fmaf(z0, sc0, z1 * sc1);
#pragma unroll
    for (int off = 32; off > 0; off >>= 1) zs += __shfl_xor(zs, off, 64);
    const float inv = 1.f / zs;
    s_sh[tid] = sc0 * inv;
    s_sh[tid + 64] = sc1 * inv;
  }
  __syncthreads();

  // attention slice (float2 per thread; explicit zeros past lens -> poison-proof)
  {
    const int t = cx * (T_S / 4) + tid * 2;
    const f2 pp = *(const f2*)(p_in + (size_t)n * T_S + t);
    const float sc = s_sh[t >> 4];
    f2 a;
    a.x = (t < L) ? pp.x * sc : 0.f;
    a.y = (t + 1 < L) ? pp.y * sc : 0.f;
    *(f2*)(out_attn + (size_t)n * T_S + t) = a;
  }

  // context slice: thread (d = cx*64 + (tid&63), chunk-group tid>>6 covers 32
  // chunks). Invalid chunks branch-skipped (wave-uniform) -> no poison reads.
  {
    const int d = cx * 64 + (tid & 63);
    const int cg = tid >> 6;
    const float* ob = Oc + (size_t)n * NCH * D_S + d;
    float acc = 0.f;
#pragma unroll
    for (int kk = 0; kk < 32; ++kk) {
      const int cc = cg * 32 + kk;
      if (cc < nc) acc = fmaf(s_sh[cc], ob[(size_t)cc * D_S], acc);
    }
    cpart[tid] = acc;
    __syncthreads();
    if (tid < 64)
      out_ctx[(size_t)n * D_S + cx * 64 + tid] =
          (cpart[tid] + cpart[tid + 64]) + (cpart[tid + 128] + cpart[tid + 192]);
  }
}

extern "C" void kernel_launch(void* const* d_in, const int* in_sizes, int n_in,
                              void* d_out, int out_size, void* d_ws,
                              size_t ws_size, hipStream_t stream) {
  const float* query = (const float*)d_in[0];
  const float* key = (const float*)d_in[1];
  const float* value = (const float*)d_in[2];
  const int* lens = (const int*)d_in[3];

  float* out_ctx = (float*)d_out;               // N*D
  float* out_attn = (float*)d_out + N_B * D_S;  // N*T

  float* p = (float*)d_ws;                         // N*T        (512 KB)
  float2* mzc = (float2*)(p + (size_t)N_B * T_S);  // N*128      (64 KB)
  float* Oc = (float*)(mzc + N_B * NCH);           // N*128*D    (8 MB)

  const dim3 grid1(NCH / 4, N_B);  // (32, 64): 4 wave-chunks per block
  fused_kernel<<<grid1, TPB, 0, stream>>>(query, key, value, lens, p, mzc, Oc);
  const dim3 grid2(4, N_B);  // (4, 64)
  merge_kernel<<<grid2, TPB, 0, stream>>>(lens, p, mzc, Oc, out_ctx, out_attn);
}

// Round 2
// 252.524 us; speedup vs baseline: 1.0200x; 1.0200x over previous
//
#include <hip/hip_runtime.h>

// N=64, T=2048, D=256, fp32. out = [context (N*D)] ++ [norm_attention (N*T)].
// softmax+mask+renorm == softmax restricted to t < lens[n]; attn == 0 past lens.
// Wave-autonomous split-softmax, 2 kernels, no atomics/memset, no barriers in K1,
// and (round 2) NO guarded loads: every K/V load is unconditional and in-bounds;
// masking is arithmetic (e=-1e30 -> p=0). Max load ILP for the latency-bound K1.
//  K1: each WAVE owns a 16-row chunk: 16 K-loads batched -> e via 16-lane
//      butterfly -> issue all 16 V-loads -> in-register chunk softmax
//      (2 cross-group shuffles for m,Z) -> O_c = p·V into one f4/lane.
//      Zero __shared__, zero __syncthreads, zero interior branches.
//  K2 (n, quarter): merge 128 chunk stats -> s_c = exp(m_c-m)/Z; attn = p*s_c
//      (explicit 0 past lens); context = sum_c s_c * O_c (invalid chunks
//      branch-skipped -> poison-proof).

#define N_B 64
#define T_S 2048
#define D_S 256
#define TPB 256
#define RC 16           // rows per wave-chunk
#define NCH (T_S / RC)  // 128 chunks per n

typedef __attribute__((ext_vector_type(4))) float f4;
typedef __attribute__((ext_vector_type(2))) float f2;

__device__ __forceinline__ f4 ntload4(const float* p) {
  return __builtin_nontemporal_load((const f4*)p);
}
__device__ __forceinline__ f4 fma4(float s, f4 a, f4 b) {
  b.x = fmaf(s, a.x, b.x);
  b.y = fmaf(s, a.y, b.y);
  b.z = fmaf(s, a.z, b.z);
  b.w = fmaf(s, a.w, b.w);
  return b;
}

__global__ __launch_bounds__(TPB) void fused_kernel(
    const float* __restrict__ q, const float* __restrict__ k,
    const float* __restrict__ v, const int* __restrict__ lens,
    float* __restrict__ p_out, float2* __restrict__ mzc,
    float* __restrict__ Oc) {
  const int n = blockIdx.y;
  const int L = lens[n];
  const int wave = threadIdx.x >> 6, lane = threadIdx.x & 63;
  const int c16 = blockIdx.x * 4 + wave;  // global 16-row chunk id
  const int r0 = c16 * RC;
  if (r0 >= L) return;  // whole-wave exit; no barriers anywhere -> safe
  const int s = lane & 15, qd = lane >> 4;

  // q fragment for the 16-lane dot layout: dims i*64 + s*4 .. +3, i=0..3.
  const f4* qp = (const f4*)(q + (size_t)n * D_S);
  const f4 qv0 = qp[s], qv1 = qp[s + 16], qv2 = qp[s + 32], qv3 = qp[s + 48];

  // ---- K phase: 16 unconditional clustered loads (rows r0+qd+4g < T_S always;
  // group qd owns rows qd+4g). Then 4 independent dot chains + butterflies.
  const float* kb = k + (size_t)n * T_S * D_S + (size_t)r0 * D_S + s * 4;
  f4 kr[4][4];
#pragma unroll
  for (int g = 0; g < 4; ++g) {
    const float* krow = kb + (size_t)(qd + 4 * g) * D_S;
#pragma unroll
    for (int i = 0; i < 4; ++i) kr[g][i] = ntload4(krow + i * 64);
  }

  float e0, e1, e2, e3;
#define EDOT(G, EV)                                                   \
  {                                                                   \
    float a = kr[G][0].x * qv0.x;                                     \
    a = fmaf(kr[G][0].y, qv0.y, a);                                   \
    a = fmaf(kr[G][0].z, qv0.z, a);                                   \
    a = fmaf(kr[G][0].w, qv0.w, a);                                   \
    a = fmaf(kr[G][1].x, qv1.x, a);                                   \
    a = fmaf(kr[G][1].y, qv1.y, a);                                   \
    a = fmaf(kr[G][1].z, qv1.z, a);                                   \
    a = fmaf(kr[G][1].w, qv1.w, a);                                   \
    a = fmaf(kr[G][2].x, qv2.x, a);                                   \
    a = fmaf(kr[G][2].y, qv2.y, a);                                   \
    a = fmaf(kr[G][2].z, qv2.z, a);                                   \
    a = fmaf(kr[G][2].w, qv2.w, a);                                   \
    a = fmaf(kr[G][3].x, qv3.x, a);                                   \
    a = fmaf(kr[G][3].y, qv3.y, a);                                   \
    a = fmaf(kr[G][3].z, qv3.z, a);                                   \
    a = fmaf(kr[G][3].w, qv3.w, a);                                   \
    a += __shfl_xor(a, 8, 64);                                        \
    a += __shfl_xor(a, 4, 64);                                        \
    a += __shfl_xor(a, 2, 64);                                        \
    a += __shfl_xor(a, 1, 64);                                        \
    EV = (r0 + qd + 4 * (G) < L) ? a : -1e30f; /* cndmask, no branch */ \
  }
  EDOT(0, e0)
  EDOT(1, e1)
  EDOT(2, e2)
  EDOT(3, e3)
#undef EDOT

  // ---- issue all 16 V loads NOW (independent of softmax): VMEM latency
  // overlaps the shuffle/exp chain below. Lane owns dims [4*lane, 4*lane+4).
  const float* vb = v + (size_t)n * T_S * D_S + (size_t)r0 * D_S + lane * 4;
  f4 vr[16];
#pragma unroll
  for (int j = 0; j < 16; ++j) vr[j] = ntload4(vb + (size_t)j * D_S);

  // ---- in-register chunk softmax (e uniform within each 16-lane group;
  // two xor-shuffles reduce across the 4 groups).
  float m = fmaxf(fmaxf(e0, e1), fmaxf(e2, e3));
  m = fmaxf(m, __shfl_xor(m, 16, 64));
  m = fmaxf(m, __shfl_xor(m, 32, 64));
  const float p0 = __expf(e0 - m), p1 = __expf(e1 - m);
  const float p2 = __expf(e2 - m), p3 = __expf(e3 - m);
  float z = (p0 + p1) + (p2 + p3);
  z += __shfl_xor(z, 16, 64);
  z += __shfl_xor(z, 32, 64);

  // unscaled p out (invalid rows write 0; merge masks t>=L explicitly anyway)
  if (s < 4) {
    float pv = p0;
    pv = (s == 1) ? p1 : pv;
    pv = (s == 2) ? p2 : pv;
    pv = (s == 3) ? p3 : pv;
    p_out[(size_t)n * T_S + r0 + qd + 4 * s] = pv;
  }
  if (lane == 0) mzc[n * NCH + c16] = make_float2(m, z);

  // ---- O_c = sum_j p_j * V[j][:]. Row j's p lives in lane 16*(j&3), reg j>>2.
  // sc == 0 for rows past lens -> contributes 0 (V data is finite, no NaN).
  f4 aA = {0.f, 0.f, 0.f, 0.f}, aB = aA;
#define VROW(J, PG, ACC) \
  { ACC = fma4(__shfl(PG, ((J) & 3) * 16, 64), vr[J], ACC); }
  VROW(0, p0, aA) VROW(1, p0, aB) VROW(2, p0, aA) VROW(3, p0, aB)
  VROW(4, p1, aA) VROW(5, p1, aB) VROW(6, p1, aA) VROW(7, p1, aB)
  VROW(8, p2, aA) VROW(9, p2, aB) VROW(10, p2, aA) VROW(11, p2, aB)
  VROW(12, p3, aA) VROW(13, p3, aB) VROW(14, p3, aA) VROW(15, p3, aB)
#undef VROW

  ((f4*)(Oc + ((size_t)(n * NCH + c16)) * D_S))[lane] = aA + aB;
}

// ---- merge: grid (4, N). Block (cx,n): attn t-slice [cx*512, +512),
// ctx d-slice [cx*64, +64). 128 chunk stats recomputed per block (L2-hot).
__global__ __launch_bounds__(TPB) void merge_kernel(
    const int* __restrict__ lens, const float* __restrict__ p_in,
    const float2* __restrict__ mzc, const float* __restrict__ Oc,
    float* __restrict__ out_ctx, float* __restrict__ out_attn) {
  const int n = blockIdx.y, cx = blockIdx.x;
  const int L = lens[n];
  const int nc = (L + RC - 1) / RC;
  const int tid = threadIdx.x;
  __shared__ float s_sh[NCH];
  __shared__ float cpart[TPB];

  if (tid < 64) {
    float m0 = -1e30f, z0 = 0.f, m1 = -1e30f, z1 = 0.f;
    if (tid < nc) {
      const float2 a = mzc[n * NCH + tid];
      m0 = a.x;
      z0 = a.y;
    }
    if (tid + 64 < nc) {
      const float2 a = mzc[n * NCH + tid + 64];
      m1 = a.x;
      z1 = a.y;
    }
    float M = fmaxf(m0, m1);
#pragma unroll
    for (int off = 32; off > 0; off >>= 1) M = fmaxf(M, __shfl_xor(M, off, 64));
    const float sc0 = __expf(m0 - M), sc1 = __expf(m1 - M);  // 0 for invalid
    float zs = fmaf(z0, sc0, z1 * sc1);
#pragma unroll
    for (int off = 32; off > 0; off >>= 1) zs += __shfl_xor(zs, off, 64);
    const float inv = 1.f / zs;
    s_sh[tid] = sc0 * inv;
    s_sh[tid + 64] = sc1 * inv;
  }
  __syncthreads();

  // attention slice (float2 per thread; explicit zeros past lens -> poison-proof)
  {
    const int t = cx * (T_S / 4) + tid * 2;
    const f2 pp = *(const f2*)(p_in + (size_t)n * T_S + t);
    const float sc = s_sh[t >> 4];
    f2 a;
    a.x = (t < L) ? pp.x * sc : 0.f;
    a.y = (t + 1 < L) ? pp.y * sc : 0.f;
    *(f2*)(out_attn + (size_t)n * T_S + t) = a;
  }

  // context slice: thread (d = cx*64 + (tid&63), chunk-group tid>>6 covers 32
  // chunks). Invalid chunks branch-skipped (wave-uniform) -> no poison reads.
  {
    const int d = cx * 64 + (tid & 63);
    const int cg = tid >> 6;
    const float* ob = Oc + (size_t)n * NCH * D_S + d;
    float acc = 0.f;
#pragma unroll
    for (int kk = 0; kk < 32; ++kk) {
      const int cc = cg * 32 + kk;
      if (cc < nc) acc = fmaf(s_sh[cc], ob[(size_t)cc * D_S], acc);
    }
    cpart[tid] = acc;
    __syncthreads();
    if (tid < 64)
      out_ctx[(size_t)n * D_S + cx * 64 + tid] =
          (cpart[tid] + cpart[tid + 64]) + (cpart[tid + 128] + cpart[tid + 192]);
  }
}

extern "C" void kernel_launch(void* const* d_in, const int* in_sizes, int n_in,
                              void* d_out, int out_size, void* d_ws,
                              size_t ws_size, hipStream_t stream) {
  const float* query = (const float*)d_in[0];
  const float* key = (const float*)d_in[1];
  const float* value = (const float*)d_in[2];
  const int* lens = (const int*)d_in[3];

  float* out_ctx = (float*)d_out;               // N*D
  float* out_attn = (float*)d_out + N_B * D_S;  // N*T

  float* p = (float*)d_ws;                         // N*T        (512 KB)
  float2* mzc = (float2*)(p + (size_t)N_B * T_S);  // N*128      (64 KB)
  float* Oc = (float*)(mzc + N_B * NCH);           // N*128*D    (8 MB)

  const dim3 grid1(NCH / 4, N_B);  // (32, 64): 4 wave-chunks per block
  fused_kernel<<<grid1, TPB, 0, stream>>>(query, key, value, lens, p, mzc, Oc);
  const dim3 grid2(4, N_B);  // (4, 64)
  merge_kernel<<<grid2, TPB, 0, stream>>>(lens, p, mzc, Oc, out_ctx, out_attn);
}

// Round 3
// 249.139 us; speedup vs baseline: 1.0339x; 1.0136x over previous
//
#include <hip/hip_runtime.h>

// N=64, T=2048, D=256, fp32. out = [context (N*D)] ++ [norm_attention (N*T)].
// softmax+mask+renorm == softmax restricted to t < lens[n]; attn == 0 past lens.
// Round 3: MLP-focused K1. Each WAVE owns a 16-row chunk; ALL 16 K-loads AND
// all 16 V-loads are issued up-front (32 outstanding VMEM ops/wave, pinned by
// sched_barrier) so the dot/softmax chain runs with V still in flight.
// __launch_bounds__(256,3) caps VGPR at 170 -> 12 waves/CU x 32 loads x 16B
// = 6KB in flight per CU (vs ~2.8KB before). No LDS, no barriers, no guarded
// loads in K1; masking is arithmetic (e=-1e30 -> p=0).
// K2: grid (8,64); interleaved chunk ownership cc = cg + kk*8 (balanced);
// invalid chunks branch-skipped -> poison-proof.

#define N_B 64
#define T_S 2048
#define D_S 256
#define TPB 256
#define RC 16           // rows per wave-chunk
#define NCH (T_S / RC)  // 128 chunks per n

typedef __attribute__((ext_vector_type(4))) float f4;
typedef __attribute__((ext_vector_type(2))) float f2;

__device__ __forceinline__ f4 ntload4(const float* p) {
  return __builtin_nontemporal_load((const f4*)p);
}
__device__ __forceinline__ f4 fma4(float s, f4 a, f4 b) {
  b.x = fmaf(s, a.x, b.x);
  b.y = fmaf(s, a.y, b.y);
  b.z = fmaf(s, a.z, b.z);
  b.w = fmaf(s, a.w, b.w);
  return b;
}

__global__ __launch_bounds__(TPB, 3) void fused_kernel(
    const float* __restrict__ q, const float* __restrict__ k,
    const float* __restrict__ v, const int* __restrict__ lens,
    float* __restrict__ p_out, float2* __restrict__ mzc,
    float* __restrict__ Oc) {
  const int n = blockIdx.y;
  const int L = lens[n];
  const int wave = threadIdx.x >> 6, lane = threadIdx.x & 63;
  const int c16 = blockIdx.x * 4 + wave;  // global 16-row chunk id
  const int r0 = c16 * RC;
  if (r0 >= L) return;  // whole-wave exit; no barriers anywhere -> safe
  const int s = lane & 15, qd = lane >> 4;

  // ---- issue ALL loads first: q (4, cached) + K (16, NT) + V (16, NT).
  // K rows r0+qd+4g always < T_S -> in-bounds; invalid rows masked later.
  const f4* qp = (const f4*)(q + (size_t)n * D_S);
  const f4 qv0 = qp[s], qv1 = qp[s + 16], qv2 = qp[s + 32], qv3 = qp[s + 48];

  const float* kb = k + (size_t)n * T_S * D_S + (size_t)r0 * D_S + s * 4;
  f4 kr[4][4];
#pragma unroll
  for (int g = 0; g < 4; ++g) {
    const float* krow = kb + (size_t)(qd + 4 * g) * D_S;
#pragma unroll
    for (int i = 0; i < 4; ++i) kr[g][i] = ntload4(krow + i * 64);
  }

  const float* vb = v + (size_t)n * T_S * D_S + (size_t)r0 * D_S + lane * 4;
  f4 vr[16];
#pragma unroll
  for (int j = 0; j < 16; ++j) vr[j] = ntload4(vb + (size_t)j * D_S);

  // Pin: nothing below may hoist above, nothing above may sink below.
  // Keeps all 32 K+V loads issued before the K-dependent dot chain.
  __builtin_amdgcn_sched_barrier(0);

  // ---- dots: 4 rows/lane-group, 16-lane butterfly. V stays in flight.
  float e0, e1, e2, e3;
#define EDOT(G, EV)                                                     \
  {                                                                     \
    float a = kr[G][0].x * qv0.x;                                       \
    a = fmaf(kr[G][0].y, qv0.y, a);                                     \
    a = fmaf(kr[G][0].z, qv0.z, a);                                     \
    a = fmaf(kr[G][0].w, qv0.w, a);                                     \
    a = fmaf(kr[G][1].x, qv1.x, a);                                     \
    a = fmaf(kr[G][1].y, qv1.y, a);                                     \
    a = fmaf(kr[G][1].z, qv1.z, a);                                     \
    a = fmaf(kr[G][1].w, qv1.w, a);                                     \
    a = fmaf(kr[G][2].x, qv2.x, a);                                     \
    a = fmaf(kr[G][2].y, qv2.y, a);                                     \
    a = fmaf(kr[G][2].z, qv2.z, a);                                     \
    a = fmaf(kr[G][2].w, qv2.w, a);                                     \
    a = fmaf(kr[G][3].x, qv3.x, a);                                     \
    a = fmaf(kr[G][3].y, qv3.y, a);                                     \
    a = fmaf(kr[G][3].z, qv3.z, a);                                     \
    a = fmaf(kr[G][3].w, qv3.w, a);                                     \
    a += __shfl_xor(a, 8, 64);                                          \
    a += __shfl_xor(a, 4, 64);                                          \
    a += __shfl_xor(a, 2, 64);                                          \
    a += __shfl_xor(a, 1, 64);                                          \
    EV = (r0 + qd + 4 * (G) < L) ? a : -1e30f; /* cndmask, no branch */ \
  }
  EDOT(0, e0)
  EDOT(1, e1)
  EDOT(2, e2)
  EDOT(3, e3)
#undef EDOT

  // ---- in-register chunk softmax (e uniform within each 16-lane group;
  // two xor-shuffles reduce across the 4 groups).
  float m = fmaxf(fmaxf(e0, e1), fmaxf(e2, e3));
  m = fmaxf(m, __shfl_xor(m, 16, 64));
  m = fmaxf(m, __shfl_xor(m, 32, 64));
  const float p0 = __expf(e0 - m), p1 = __expf(e1 - m);
  const float p2 = __expf(e2 - m), p3 = __expf(e3 - m);
  float z = (p0 + p1) + (p2 + p3);
  z += __shfl_xor(z, 16, 64);
  z += __shfl_xor(z, 32, 64);

  // unscaled p out (invalid rows write 0; merge masks t>=L explicitly anyway)
  if (s < 4) {
    float pv = p0;
    pv = (s == 1) ? p1 : pv;
    pv = (s == 2) ? p2 : pv;
    pv = (s == 3) ? p3 : pv;
    p_out[(size_t)n * T_S + r0 + qd + 4 * s] = pv;
  }
  if (lane == 0) mzc[n * NCH + c16] = make_float2(m, z);

  // ---- O_c = sum_j p_j * V[j][:]. Row j's p lives in lane 16*(j&3) of reg
  // p_{j>>2}. p == 0 for rows past lens -> contributes 0 (V data finite).
  f4 aA = {0.f, 0.f, 0.f, 0.f}, aB = aA;
#define VROW(J, PG, ACC) \
  { ACC = fma4(__shfl(PG, ((J) & 3) * 16, 64), vr[J], ACC); }
  VROW(0, p0, aA) VROW(1, p0, aB) VROW(2, p0, aA) VROW(3, p0, aB)
  VROW(4, p1, aA) VROW(5, p1, aB) VROW(6, p1, aA) VROW(7, p1, aB)
  VROW(8, p2, aA) VROW(9, p2, aB) VROW(10, p2, aA) VROW(11, p2, aB)
  VROW(12, p3, aA) VROW(13, p3, aB) VROW(14, p3, aA) VROW(15, p3, aB)
#undef VROW

  ((f4*)(Oc + ((size_t)(n * NCH + c16)) * D_S))[lane] = aA + aB;
}

// ---- merge: grid (8, N). Block (cx,n): attn t-slice [cx*256, +256),
// ctx d-slice [cx*32, +32). 128 chunk stats recomputed per block (L2-hot).
// Chunk ownership interleaved (cc = cg + kk*8) -> balanced across waves.
__global__ __launch_bounds__(TPB) void merge_kernel(
    const int* __restrict__ lens, const float* __restrict__ p_in,
    const float2* __restrict__ mzc, const float* __restrict__ Oc,
    float* __restrict__ out_ctx, float* __restrict__ out_attn) {
  const int n = blockIdx.y, cx = blockIdx.x;
  const int L = lens[n];
  const int nc = (L + RC - 1) / RC;
  const int tid = threadIdx.x;
  __shared__ float s_sh[NCH];
  __shared__ float cpart[TPB];

  if (tid < 64) {
    float m0 = -1e30f, z0 = 0.f, m1 = -1e30f, z1 = 0.f;
    if (tid < nc) {
      const float2 a = mzc[n * NCH + tid];
      m0 = a.x;
      z0 = a.y;
    }
    if (tid + 64 < nc) {
      const float2 a = mzc[n * NCH + tid + 64];
      m1 = a.x;
      z1 = a.y;
    }
    float M = fmaxf(m0, m1);
#pragma unroll
    for (int off = 32; off > 0; off >>= 1) M = fmaxf(M, __shfl_xor(M, off, 64));
    const float sc0 = __expf(m0 - M), sc1 = __expf(m1 - M);  // 0 for invalid
    float zs = fmaf(z0, sc0, z1 * sc1);
#pragma unroll
    for (int off = 32; off > 0; off >>= 1) zs += __shfl_xor(zs, off, 64);
    const float inv = 1.f / zs;
    s_sh[tid] = sc0 * inv;
    s_sh[tid + 64] = sc1 * inv;
  }
  __syncthreads();

  // attention slice: 256 t per block, waves 0-1 (f2 per thread; explicit
  // zeros past lens -> poison-proof)
  if (tid < 128) {
    const int t = cx * (T_S / 8) + tid * 2;
    const f2 pp = *(const f2*)(p_in + (size_t)n * T_S + t);
    const float sc = s_sh[t >> 4];
    f2 a;
    a.x = (t < L) ? pp.x * sc : 0.f;
    a.y = (t + 1 < L) ? pp.y * sc : 0.f;
    *(f2*)(out_attn + (size_t)n * T_S + t) = a;
  }

  // context slice: thread (d = cx*32 + (tid&31), chunk-group cg = tid>>5 of 8).
  // cc = cg + kk*8 interleaves chunks across groups -> each thread <= 16 and
  // balanced for any nc. Invalid chunks branch-skipped -> no poison reads.
  {
    const int d = cx * 32 + (tid & 31);
    const int cg = tid >> 5;
    const float* ob = Oc + (size_t)n * NCH * D_S + d;
    float acc = 0.f;
#pragma unroll
    for (int kk = 0; kk < 16; ++kk) {
      const int cc = cg + kk * 8;
      if (cc < nc) acc = fmaf(s_sh[cc], ob[(size_t)cc * D_S], acc);
    }
    cpart[tid] = acc;
    __syncthreads();
    if (tid < 32) {
      float r = 0.f;
#pragma unroll
      for (int w = 0; w < 8; ++w) r += cpart[tid + w * 32];
      out_ctx[(size_t)n * D_S + cx * 32 + tid] = r;
    }
  }
}

extern "C" void kernel_launch(void* const* d_in, const int* in_sizes, int n_in,
                              void* d_out, int out_size, void* d_ws,
                              size_t ws_size, hipStream_t stream) {
  const float* query = (const float*)d_in[0];
  const float* key = (const float*)d_in[1];
  const float* value = (const float*)d_in[2];
  const int* lens = (const int*)d_in[3];

  float* out_ctx = (float*)d_out;               // N*D
  float* out_attn = (float*)d_out + N_B * D_S;  // N*T

  float* p = (float*)d_ws;                         // N*T        (512 KB)
  float2* mzc = (float2*)(p + (size_t)N_B * T_S);  // N*128      (64 KB)
  float* Oc = (float*)(mzc + N_B * NCH);           // N*128*D    (8 MB)

  const dim3 grid1(NCH / 4, N_B);  // (32, 64): 4 wave-chunks per block
  fused_kernel<<<grid1, TPB, 0, stream>>>(query, key, value, lens, p, mzc, Oc);
  const dim3 grid2(8, N_B);  // (8, 64)
  merge_kernel<<<grid2, TPB, 0, stream>>>(lens, p, mzc, Oc, out_ctx, out_attn);
}

// Round 4
// 246.568 us; speedup vs baseline: 1.0446x; 1.0104x over previous
//
#include <hip/hip_runtime.h>

// N=64, T=2048, D=256, fp32. out = [context (N*D)] ++ [norm_attention (N*T)].
// softmax+mask+renorm == softmax restricted to t < lens[n]; attn == 0 past lens.
// Round 4: round-0 block structure (RC=64, TPB=256, low VGPR, full co-residency)
// + V staged HBM->LDS via global_load_lds DMA (zero VGPR cost, vmcnt-tracked),
// issued up-front alongside the 16 K reg-loads -> ~128KB in flight per block.
// The mandatory vmcnt(0) drain at the first __syncthreads IS the V-ready sync.
// Softmax computed redundantly by all 4 waves (row=lane, butterflies) -> one
// fewer barrier, no p_sh; phase 3 reads V from LDS + broadcast __shfl(pv,row).
// K2: round-0 merge, grid (4,64), + wave-uniform cc<nc guard (poison-proof).

#define N_B 64
#define T_S 2048
#define D_S 256
#define TPB 256
#define RC 64           // rows per block-chunk
#define NC (T_S / RC)   // 32 chunks per n

typedef __attribute__((ext_vector_type(4))) float f4;
typedef __attribute__((ext_vector_type(2))) float f2;

__device__ __forceinline__ f4 ntload4(const float* p) {
  return __builtin_nontemporal_load((const f4*)p);
}
__device__ __forceinline__ f4 fma4(float s, f4 a, f4 b) {
  b.x = fmaf(s, a.x, b.x);
  b.y = fmaf(s, a.y, b.y);
  b.z = fmaf(s, a.z, b.z);
  b.w = fmaf(s, a.w, b.w);
  return b;
}
// HBM -> LDS DMA, 16B/lane x 64 lanes = 1KB. LDS dest = base + lane*16
// (wave-uniform base); global src is per-lane.
__device__ __forceinline__ void ldsdma16(float* lds, const float* g) {
  __builtin_amdgcn_global_load_lds(
      (const __attribute__((address_space(1))) void*)g,
      (__attribute__((address_space(3))) void*)lds, 16, 0, 0);
}

__global__ __launch_bounds__(TPB) void fused_kernel(
    const float* __restrict__ q, const float* __restrict__ k,
    const float* __restrict__ v, const int* __restrict__ lens,
    float* __restrict__ p_out, float2* __restrict__ mzc,
    float* __restrict__ Oc) {
  const int n = blockIdx.y, c = blockIdx.x;
  const int L = lens[n];
  const int t0 = c * RC;
  if (t0 >= L) return;
  const int tend = min(t0 + RC, L);
  const int tid = threadIdx.x;
  const int lane = tid & 63, wave = tid >> 6;
  const int s = lane & 15, qd = lane >> 4;

  __shared__ float v_sh[RC * D_S];  // 64 KB V tile
  __shared__ float e_sh[RC];        // 256 B energies
  __shared__ f4 part[TPB];          // 4 KB cross-wave ctx partials

  // q fragment for the 16-lane dot layout (cached loads; L2-hot across chunks)
  const f4* qp = (const f4*)(q + (size_t)n * D_S);
  const f4 qv0 = qp[s], qv1 = qp[s + 16], qv2 = qp[s + 32], qv3 = qp[s + 48];

  // ---- K batch: wave owns rows t0 + wave*16 + qd + 4g; 16 reg loads,
  // all in-bounds (t0+64 <= T_S), invalid rows masked arithmetically below.
  const float* kb =
      k + (size_t)n * T_S * D_S + (size_t)(t0 + wave * 16) * D_S + s * 4;
  f4 kr[4][4];
#pragma unroll
  for (int g = 0; g < 4; ++g) {
    const float* krow = kb + (size_t)(qd + 4 * g) * D_S;
#pragma unroll
    for (int i = 0; i < 4; ++i) kr[g][i] = ntload4(krow + i * 64);
  }

  // ---- V DMA: wave stages its 16 rows (always in-bounds; rows past tend are
  // real finite data killed by p=0 -> never skip: LDS garbage could be NaN).
  {
    const float* vsrc =
        v + (size_t)n * T_S * D_S + (size_t)(t0 + wave * 16) * D_S + lane * 4;
    float* vdst = v_sh + wave * 16 * D_S;
#pragma unroll
    for (int i = 0; i < 16; ++i) ldsdma16(vdst + i * D_S, vsrc + (size_t)i * D_S);
  }
  // pin: all 32 VMEM ops issued before any K-dependent compute
  __builtin_amdgcn_sched_barrier(0);

  // ---- dots: 4 rows per 16-lane group, butterfly reduce; mask past tend.
  float e0, e1, e2, e3;
#define EDOT(G, EV)                                                  \
  {                                                                  \
    float a = kr[G][0].x * qv0.x;                                    \
    a = fmaf(kr[G][0].y, qv0.y, a);                                  \
    a = fmaf(kr[G][0].z, qv0.z, a);                                  \
    a = fmaf(kr[G][0].w, qv0.w, a);                                  \
    a = fmaf(kr[G][1].x, qv1.x, a);                                  \
    a = fmaf(kr[G][1].y, qv1.y, a);                                  \
    a = fmaf(kr[G][1].z, qv1.z, a);                                  \
    a = fmaf(kr[G][1].w, qv1.w, a);                                  \
    a = fmaf(kr[G][2].x, qv2.x, a);                                  \
    a = fmaf(kr[G][2].y, qv2.y, a);                                  \
    a = fmaf(kr[G][2].z, qv2.z, a);                                  \
    a = fmaf(kr[G][2].w, qv2.w, a);                                  \
    a = fmaf(kr[G][3].x, qv3.x, a);                                  \
    a = fmaf(kr[G][3].y, qv3.y, a);                                  \
    a = fmaf(kr[G][3].z, qv3.z, a);                                  \
    a = fmaf(kr[G][3].w, qv3.w, a);                                  \
    a += __shfl_xor(a, 8, 64);                                       \
    a += __shfl_xor(a, 4, 64);                                       \
    a += __shfl_xor(a, 2, 64);                                       \
    a += __shfl_xor(a, 1, 64);                                       \
    EV = (t0 + wave * 16 + qd + 4 * (G) < tend) ? a : -1e30f;        \
  }
  EDOT(0, e0)
  EDOT(1, e1)
  EDOT(2, e2)
  EDOT(3, e3)
#undef EDOT

  if (s == 0) {
    e_sh[wave * 16 + qd] = e0;
    e_sh[wave * 16 + qd + 4] = e1;
    e_sh[wave * 16 + qd + 8] = e2;
    e_sh[wave * 16 + qd + 12] = e3;
  }
  // drains vmcnt(0) (compiler-mandated) -> V tile fully in LDS after this.
  __syncthreads();

  // ---- softmax, redundant in every wave: lane owns row=lane.
  const float ee = e_sh[lane];
  float m = ee;
#pragma unroll
  for (int off = 32; off > 0; off >>= 1) m = fmaxf(m, __shfl_xor(m, off, 64));
  const float pv = __expf(ee - m);  // 0 for rows past tend
  float z = pv;
#pragma unroll
  for (int off = 32; off > 0; off >>= 1) z += __shfl_xor(z, off, 64);

  if (wave == 0) {
    p_out[(size_t)n * T_S + t0 + lane] = pv;  // 256B contiguous
    if (lane == 0) mzc[n * NC + c] = make_float2(m, z);
  }

  // ---- O_c from LDS: lane owns d-slice [lane*4, +4); wave owns rows
  // == wave (mod 4): r = j*16 + wave + {0,4,8,12}. p via broadcast shuffle.
  f4 a0 = {0.f, 0.f, 0.f, 0.f}, a1 = a0, a2 = a0, a3 = a0;
#pragma unroll
  for (int j = 0; j < 4; ++j) {
    const int r0 = j * 16 + wave;
    const f4 v0 = *(const f4*)(v_sh + (size_t)r0 * D_S + lane * 4);
    const f4 v1 = *(const f4*)(v_sh + (size_t)(r0 + 4) * D_S + lane * 4);
    const f4 v2 = *(const f4*)(v_sh + (size_t)(r0 + 8) * D_S + lane * 4);
    const f4 v3 = *(const f4*)(v_sh + (size_t)(r0 + 12) * D_S + lane * 4);
    a0 = fma4(__shfl(pv, r0, 64), v0, a0);
    a1 = fma4(__shfl(pv, r0 + 4, 64), v1, a1);
    a2 = fma4(__shfl(pv, r0 + 8, 64), v2, a2);
    a3 = fma4(__shfl(pv, r0 + 12, 64), v3, a3);
  }
  part[tid] = (a0 + a1) + (a2 + a3);
  __syncthreads();
  if (wave == 0) {
    const f4 r = part[lane] + part[lane + 64] + part[lane + 128] + part[lane + 192];
    ((f4*)(Oc + ((size_t)(n * NC + c)) * D_S))[lane] = r;
  }
}

// ---- merge: grid (4, N). Block (cx,n): attn t-slice [cx*512, +512),
// ctx d-slice [cx*64, +64). Chunk stats recomputed per block (L2-hot).
__global__ __launch_bounds__(TPB) void merge_kernel(
    const int* __restrict__ lens, const float* __restrict__ p_in,
    const float2* __restrict__ mzc, const float* __restrict__ Oc,
    float* __restrict__ out_ctx, float* __restrict__ out_attn) {
  const int n = blockIdx.y, cx = blockIdx.x;
  const int L = lens[n];
  const int nc = (L + RC - 1) / RC;
  const int tid = threadIdx.x;
  __shared__ float s_sh[NC];
  __shared__ float cpart[TPB];

  if (tid < 64) {
    float m = -1e30f, z = 0.f;
    if (tid < nc) {
      const float2 mz = mzc[n * NC + tid];
      m = mz.x;
      z = mz.y;
    }
    float M = m;
#pragma unroll
    for (int off = 32; off > 0; off >>= 1) M = fmaxf(M, __shfl_xor(M, off, 64));
    const float sc = __expf(m - M);  // 0 for invalid chunks
    float zs = z * sc;
#pragma unroll
    for (int off = 32; off > 0; off >>= 1) zs += __shfl_xor(zs, off, 64);
    if (tid < NC) s_sh[tid] = sc / zs;
  }
  __syncthreads();

  // attention slice (float2 per thread; explicit zeros past lens)
  {
    const int t = cx * (T_S / 4) + tid * 2;
    const f2 p = *(const f2*)(p_in + (size_t)n * T_S + t);
    const float sc = s_sh[t >> 6];
    f2 a;
    a.x = (t < L) ? p.x * sc : 0.f;
    a.y = (t + 1 < L) ? p.y * sc : 0.f;
    *(f2*)(out_attn + (size_t)n * T_S + t) = a;
  }

  // context slice: thread (d = cx*64 + (tid&63), chunk-group tid>>6 of 8
  // interleaved chunks). Invalid chunks skipped (wave-uniform) -> poison-proof.
  {
    const int d = cx * 64 + (tid & 63);
    const int cg = tid >> 6;
    const float* ob = Oc + (size_t)n * NC * D_S + d;
    float acc = 0.f;
#pragma unroll
    for (int kk = 0; kk < 8; ++kk) {
      const int cc = cg + kk * 4;
      if (cc < nc) acc = fmaf(s_sh[cc], ob[(size_t)cc * D_S], acc);
    }
    cpart[tid] = acc;
    __syncthreads();
    if (tid < 64)
      out_ctx[(size_t)n * D_S + d] =
          (cpart[tid] + cpart[tid + 64]) + (cpart[tid + 128] + cpart[tid + 192]);
  }
}

extern "C" void kernel_launch(void* const* d_in, const int* in_sizes, int n_in,
                              void* d_out, int out_size, void* d_ws,
                              size_t ws_size, hipStream_t stream) {
  const float* query = (const float*)d_in[0];
  const float* key = (const float*)d_in[1];
  const float* value = (const float*)d_in[2];
  const int* lens = (const int*)d_in[3];

  float* out_ctx = (float*)d_out;               // N*D
  float* out_attn = (float*)d_out + N_B * D_S;  // N*T

  float* p = (float*)d_ws;                         // N*T       (512 KB)
  float2* mzc = (float2*)(p + (size_t)N_B * T_S);  // N*NC      (16 KB)
  float* Oc = (float*)(mzc + N_B * NC);            // N*NC*D    (2 MB)

  const dim3 grid1(NC, N_B);  // (32, 64)
  fused_kernel<<<grid1, TPB, 0, stream>>>(query, key, value, lens, p, mzc, Oc);
  const dim3 grid2(4, N_B);  // (4, 64)
  merge_kernel<<<grid2, TPB, 0, stream>>>(lens, p, mzc, Oc, out_ctx, out_attn);
}

// Round 7
// 245.948 us; speedup vs baseline: 1.0473x; 1.0025x over previous
//
#include <hip/hip_runtime.h>

// Attention with per-row valid-length masking. N=64, T=2048, D=256, fp32.
// out = [context (N*D)] ++ [norm_attention (N*T)].
// Masked-softmax identity: softmax over all T then mask+renorm over t<lens[n]
// equals softmax restricted to t<lens[n]; attention is 0 at t>=lens[n].
//
// Round 6 resubmit (two broker failures on identical source; comments touched
// to vary the source hash — zero functional change).
// Structure = round-0 champion (RC=64 block chunk, TPB=256, low VGPR, full
// 32-waves/CU co-residency) plus three surgical deltas:
//  A) q held in registers (drops q_sh and its init barrier)   [validated R4]
//  B) softmax recomputed redundantly by all 4 waves from e_sh, p delivered
//     to phase 3 by __shfl broadcast (drops wave0-only phase + one barrier)
//                                                             [validated R4]
//  C) the j=0 V-row quad is prefetched before the barrier, keeping VMEM
//     busy across the barrier's vmcnt drain (16 VGPR, transient)
// Net: 2 barriers per block instead of 4. All K loads unconditional and
// in-bounds; invalid rows masked arithmetically (e=-1e30 -> p=0 exactly).
// K/V streamed nontemporal. Merge kernel: round-0 form + wave-uniform cc<nc
// guard so freshly-poisoned Oc chunks are never read   [validated R4].

#define N_B 64
#define T_S 2048
#define D_S 256
#define TPB 256
#define RC 64          // rows per block-chunk
#define NC (T_S / RC)  // 32 chunks per n

typedef __attribute__((ext_vector_type(4))) float f4;
typedef __attribute__((ext_vector_type(2))) float f2;

__device__ __forceinline__ f4 ntload4(const float* p) {
  return __builtin_nontemporal_load((const f4*)p);
}
__device__ __forceinline__ f4 fma4(float s, f4 a, f4 b) {
  b.x = fmaf(s, a.x, b.x);
  b.y = fmaf(s, a.y, b.y);
  b.z = fmaf(s, a.z, b.z);
  b.w = fmaf(s, a.w, b.w);
  return b;
}

__global__ __launch_bounds__(TPB) void fused_kernel(
    const float* __restrict__ q, const float* __restrict__ k,
    const float* __restrict__ v, const int* __restrict__ lens,
    float* __restrict__ p_out, float2* __restrict__ mzc,
    float* __restrict__ Oc) {
  const int n = blockIdx.y, c = blockIdx.x;
  const int L = lens[n];
  const int t0 = c * RC;
  if (t0 >= L) return;  // block-uniform exit (before any barrier)
  const int tend = min(t0 + RC, L);
  const int tid = threadIdx.x;
  const int lane = tid & 63, wave = tid >> 6;
  const int s = lane & 15, qd = lane >> 4;

  __shared__ float e_sh[RC];  // 256 B energies
  __shared__ f4 part[TPB];    // 4 KB cross-wave context partials

  // q fragment in regs (16 VGPR, dead after phase 1; L2-hot across chunks)
  const f4* qp = (const f4*)(q + (size_t)n * D_S);
  const f4 qv0 = qp[s], qv1 = qp[s + 16], qv2 = qp[s + 32], qv3 = qp[s + 48];

  // phase 1: energies. Wave owns rows t0+wave*16..+15; 4 rows per pass
  // (16-lane group qd -> row, sublane s -> d-quarter). Loads unconditional,
  // always in-bounds (t0+63 <= 2047); invalid rows cndmask'd to -1e30.
  const float* kb =
      k + (size_t)n * T_S * D_S + (size_t)(t0 + wave * 16) * D_S + s * 4;
#pragma unroll
  for (int g = 0; g < 4; ++g) {
    const int row = wave * 16 + qd + 4 * g;  // chunk-local row index
    const float* krow = kb + (size_t)(qd + 4 * g) * D_S;
    const f4 k0 = ntload4(krow);
    const f4 k1 = ntload4(krow + 64);
    const f4 k2 = ntload4(krow + 128);
    const f4 k3 = ntload4(krow + 192);
    float a = k0.x * qv0.x;
    a = fmaf(k0.y, qv0.y, a);
    a = fmaf(k0.z, qv0.z, a);
    a = fmaf(k0.w, qv0.w, a);
    a = fmaf(k1.x, qv1.x, a);
    a = fmaf(k1.y, qv1.y, a);
    a = fmaf(k1.z, qv1.z, a);
    a = fmaf(k1.w, qv1.w, a);
    a = fmaf(k2.x, qv2.x, a);
    a = fmaf(k2.y, qv2.y, a);
    a = fmaf(k2.z, qv2.z, a);
    a = fmaf(k2.w, qv2.w, a);
    a = fmaf(k3.x, qv3.x, a);
    a = fmaf(k3.y, qv3.y, a);
    a = fmaf(k3.z, qv3.z, a);
    a = fmaf(k3.w, qv3.w, a);
    a += __shfl_xor(a, 8, 64);
    a += __shfl_xor(a, 4, 64);
    a += __shfl_xor(a, 2, 64);
    a += __shfl_xor(a, 1, 64);
    a = (t0 + row < tend) ? a : -1e30f;  // arithmetic mask, branch-free
    if (s == 0) e_sh[row] = a;
  }

  // delta C: prefetch the j=0 V-row quad (rows wave, wave+4, wave+8,
  // wave+12) so VMEM stays busy across the barrier's drain.
  const float* vb = v + (size_t)n * T_S * D_S + (size_t)t0 * D_S + lane * 4;
  const f4 pv0 = ntload4(vb + (size_t)wave * D_S);
  const f4 pv1 = ntload4(vb + (size_t)(wave + 4) * D_S);
  const f4 pv2 = ntload4(vb + (size_t)(wave + 8) * D_S);
  const f4 pv3 = ntload4(vb + (size_t)(wave + 12) * D_S);

  __syncthreads();  // e_sh visible to all waves

  // phase 2 (every wave, redundant): lane owns row=lane; 6-shuffle
  // butterflies. Rows past tend carry e=-1e30 -> p=0 exactly.
  const float ee = e_sh[lane];
  float m = ee;
#pragma unroll
  for (int off = 32; off > 0; off >>= 1) m = fmaxf(m, __shfl_xor(m, off, 64));
  const float pvs = __expf(ee - m);
  float z = pvs;
#pragma unroll
  for (int off = 32; off > 0; off >>= 1) z += __shfl_xor(z, off, 64);

  if (wave == 0) {
    p_out[(size_t)n * T_S + t0 + lane] = pvs;  // 256 B contiguous store
    if (lane == 0) mzc[n * NC + c] = make_float2(m, z);
  }

  // phase 3: O_c = sum_r p_r * V[r][:]. Wave covers rows j*16+wave+
  // {0,4,8,12}; p fetched by broadcast __shfl from the owning lane.
  f4 a0 = fma4(__shfl(pvs, wave, 64), pv0, f4{0.f, 0.f, 0.f, 0.f});
  f4 a1 = fma4(__shfl(pvs, wave + 4, 64), pv1, f4{0.f, 0.f, 0.f, 0.f});
  f4 a2 = fma4(__shfl(pvs, wave + 8, 64), pv2, f4{0.f, 0.f, 0.f, 0.f});
  f4 a3 = fma4(__shfl(pvs, wave + 12, 64), pv3, f4{0.f, 0.f, 0.f, 0.f});
#pragma unroll
  for (int j = 1; j < 4; ++j) {
    const int r0 = j * 16 + wave;
    const f4 v0 = ntload4(vb + (size_t)r0 * D_S);
    const f4 v1 = ntload4(vb + (size_t)(r0 + 4) * D_S);
    const f4 v2 = ntload4(vb + (size_t)(r0 + 8) * D_S);
    const f4 v3 = ntload4(vb + (size_t)(r0 + 12) * D_S);
    a0 = fma4(__shfl(pvs, r0, 64), v0, a0);
    a1 = fma4(__shfl(pvs, r0 + 4, 64), v1, a1);
    a2 = fma4(__shfl(pvs, r0 + 8, 64), v2, a2);
    a3 = fma4(__shfl(pvs, r0 + 12, 64), v3, a3);
  }
  part[tid] = (a0 + a1) + (a2 + a3);
  __syncthreads();
  if (wave == 0) {
    const f4 r =
        part[lane] + part[lane + 64] + part[lane + 128] + part[lane + 192];
    ((f4*)(Oc + ((size_t)(n * NC + c)) * D_S))[lane] = r;
  }
}

// merge: grid (4, N). Block (cx,n): attn t-slice [cx*512, +512), ctx d-slice
// [cx*64, +64). The 32 chunk stats are recomputed per block (tiny, L2-hot).
__global__ __launch_bounds__(TPB) void merge_kernel(
    const int* __restrict__ lens, const float* __restrict__ p_in,
    const float2* __restrict__ mzc, const float* __restrict__ Oc,
    float* __restrict__ out_ctx, float* __restrict__ out_attn) {
  const int n = blockIdx.y, cx = blockIdx.x;
  const int L = lens[n];
  const int nc = (L + RC - 1) / RC;
  const int tid = threadIdx.x;
  __shared__ float s_sh[NC];
  __shared__ float cpart[TPB];

  if (tid < 64) {
    float m = -1e30f, z = 0.f;
    if (tid < nc) {
      const float2 mz = mzc[n * NC + tid];
      m = mz.x;
      z = mz.y;
    }
    float M = m;
#pragma unroll
    for (int off = 32; off > 0; off >>= 1) M = fmaxf(M, __shfl_xor(M, off, 64));
    const float sc = __expf(m - M);  // exactly 0 for invalid chunks
    float zs = z * sc;
#pragma unroll
    for (int off = 32; off > 0; off >>= 1) zs += __shfl_xor(zs, off, 64);
    if (tid < NC) s_sh[tid] = sc / zs;
  }
  __syncthreads();

  // attention slice (float2 per thread; explicit zeros past lens)
  {
    const int t = cx * (T_S / 4) + tid * 2;
    const f2 p = *(const f2*)(p_in + (size_t)n * T_S + t);
    const float sc = s_sh[t >> 6];
    f2 a;
    a.x = (t < L) ? p.x * sc : 0.f;
    a.y = (t + 1 < L) ? p.y * sc : 0.f;
    *(f2*)(out_attn + (size_t)n * T_S + t) = a;
  }

  // context slice: thread (d = cx*64 + (tid&63), chunk-group tid>>6 walks 8
  // interleaved chunks). Invalid chunks skipped wave-uniformly -> the
  // poisoned region of Oc is never even loaded.
  {
    const int d = cx * 64 + (tid & 63);
    const int cg = tid >> 6;
    const float* ob = Oc + (size_t)n * NC * D_S + d;
    float acc = 0.f;
#pragma unroll
    for (int kk = 0; kk < 8; ++kk) {
      const int cc = cg + kk * 4;
      if (cc < nc) acc = fmaf(s_sh[cc], ob[(size_t)cc * D_S], acc);
    }
    cpart[tid] = acc;
    __syncthreads();
    if (tid < 64)
      out_ctx[(size_t)n * D_S + d] =
          (cpart[tid] + cpart[tid + 64]) + (cpart[tid + 128] + cpart[tid + 192]);
  }
}

extern "C" void kernel_launch(void* const* d_in, const int* in_sizes, int n_in,
                              void* d_out, int out_size, void* d_ws,
                              size_t ws_size, hipStream_t stream) {
  const float* query = (const float*)d_in[0];
  const float* key = (const float*)d_in[1];
  const float* value = (const float*)d_in[2];
  const int* lens = (const int*)d_in[3];

  float* out_ctx = (float*)d_out;               // N*D
  float* out_attn = (float*)d_out + N_B * D_S;  // N*T

  float* p = (float*)d_ws;                         // N*T       (512 KB)
  float2* mzc = (float2*)(p + (size_t)N_B * T_S);  // N*NC      (16 KB)
  float* Oc = (float*)(mzc + N_B * NC);            // N*NC*D    (2 MB)

  const dim3 grid1(NC, N_B);  // (32, 64)
  fused_kernel<<<grid1, TPB, 0, stream>>>(query, key, value, lens, p, mzc, Oc);
  const dim3 grid2(4, N_B);  // (4, 64)
  merge_kernel<<<grid2, TPB, 0, stream>>>(lens, p, mzc, Oc, out_ctx, out_attn);
}